// Round 2
// baseline (280.544 us; speedup 1.0000x reference)
//
#include <hip/hip_runtime.h>
#include <hip/hip_bf16.h>

#define LRELU_ALPHA 0.2f

typedef unsigned short u16;

__device__ __forceinline__ float bflo(unsigned int d) {
    union { unsigned int i; float f; } u; u.i = d << 16; return u.f;
}
__device__ __forceinline__ float bfhi(unsigned int d) {
    union { unsigned int i; float f; } u; u.i = d & 0xffff0000u; return u.f;
}
__device__ __forceinline__ void unpack8(uint4 v, float* o) {
    o[0] = bflo(v.x); o[1] = bfhi(v.x);
    o[2] = bflo(v.y); o[3] = bfhi(v.y);
    o[4] = bflo(v.z); o[5] = bfhi(v.z);
    o[6] = bflo(v.w); o[7] = bfhi(v.w);
}
__device__ __forceinline__ u16 f2bf(float f) {
    union { float f; unsigned int i; } u; u.f = f;
    unsigned int r = (u.i + 0x7fffu + ((u.i >> 16) & 1u)) >> 16;
    return (u16)r;
}

// Attention layer core: per-thread = (row i = t>>1, col half o0 = (t&1)*32).
// ELU: apply elu before LN (layer 1).  RESID: h = relu(h' + sH_row) before LN (layer 2).
template<bool ELU, bool RESID>
__device__ __forceinline__ void att_layer(
    int t, const float* __restrict__ ADJ,
    const float* __restrict__ sWh, float* __restrict__ sH,
    const float* __restrict__ sEi, const float* __restrict__ sEj,
    const float* __restrict__ LNG, const float* __restrict__ LNB)
{
    const int i  = t >> 1;
    const int o0 = (t & 1) * 32;
    const float ei = sEi[i];
    const float4* arow = (const float4*)(ADJ + i * 128);

    // pass A: row max over masked entries (diagonal always unmasked: adj_ii >= 1)
    float m = -3.0e38f;
    for (int j4 = 0; j4 < 32; ++j4) {
        float4 a = arow[j4];
        const float* ejp = sEj + j4 * 4;
        float e0 = ei + ejp[0]; e0 = (e0 >= 0.f) ? e0 : LRELU_ALPHA * e0;
        float e1 = ei + ejp[1]; e1 = (e1 >= 0.f) ? e1 : LRELU_ALPHA * e1;
        float e2 = ei + ejp[2]; e2 = (e2 >= 0.f) ? e2 : LRELU_ALPHA * e2;
        float e3 = ei + ejp[3]; e3 = (e3 >= 0.f) ? e3 : LRELU_ALPHA * e3;
        if (a.x > 0.f) m = fmaxf(m, e0);
        if (a.y > 0.f) m = fmaxf(m, e1);
        if (a.z > 0.f) m = fmaxf(m, e2);
        if (a.w > 0.f) m = fmaxf(m, e3);
    }

    // pass B: weights + denominator + accumulate att @ Wh
    float D = 0.f;
    float acc[32];
    #pragma unroll
    for (int q = 0; q < 32; ++q) acc[q] = 0.f;

    for (int j4 = 0; j4 < 32; ++j4) {
        float4 a = arow[j4];
        float a4[4] = { a.x, a.y, a.z, a.w };
        #pragma unroll
        for (int k = 0; k < 4; ++k) {
            const int j = j4 * 4 + k;
            float e = ei + sEj[j];
            e = (e >= 0.f) ? e : LRELU_ALPHA * e;
            float w = (a4[k] > 0.f) ? (__expf(e - m) * a4[k]) : 0.f;
            D += w;
            const float4* wh = (const float4*)(sWh + j * 68 + o0);
            #pragma unroll
            for (int q = 0; q < 8; ++q) {
                float4 v = wh[q];
                acc[q * 4 + 0] += w * v.x;
                acc[q * 4 + 1] += w * v.y;
                acc[q * 4 + 2] += w * v.z;
                acc[q * 4 + 3] += w * v.w;
            }
        }
    }

    // epilogue: normalize, activation / residual, LayerNorm over the 64-wide row
    const float r = 1.f / D;
    float vb[32];
    float s1 = 0.f, s2 = 0.f;
    #pragma unroll
    for (int q = 0; q < 32; ++q) {
        float x = acc[q] * r;
        if (ELU)   x = (x > 0.f) ? x : (__expf(x) - 1.f);
        if (RESID) x = fmaxf(x + sH[i * 68 + o0 + q], 0.f);
        vb[q] = x; s1 += x; s2 += x * x;
    }
    s1 += __shfl_xor(s1, 1);
    s2 += __shfl_xor(s2, 1);
    const float mean = s1 * (1.f / 64.f);
    const float var  = s2 * (1.f / 64.f) - mean * mean;
    const float rstd = rsqrtf(var + 1e-5f);
    #pragma unroll
    for (int q4 = 0; q4 < 8; ++q4) {
        float4 g = *(const float4*)(LNG + o0 + q4 * 4);
        float4 bb = *(const float4*)(LNB + o0 + q4 * 4);
        float* dst = sH + i * 68 + o0 + q4 * 4;
        dst[0] = (vb[q4 * 4 + 0] - mean) * rstd * g.x + bb.x;
        dst[1] = (vb[q4 * 4 + 1] - mean) * rstd * g.y + bb.y;
        dst[2] = (vb[q4 * 4 + 2] - mean) * rstd * g.z + bb.z;
        dst[3] = (vb[q4 * 4 + 3] - mean) * rstd * g.w + bb.w;
    }
}

__global__ __launch_bounds__(256, 2) void graphmixer_kernel(
    const float* __restrict__ C,     // (1024,128)
    const float* __restrict__ ADJ,   // (128,128)
    const float* __restrict__ EMB,   // (128,8)
    const float* __restrict__ W1,    // (9,64)
    const float* __restrict__ A1,    // (128)
    const float* __restrict__ W2,    // (64,64)
    const float* __restrict__ A2,    // (128)
    const float* __restrict__ LN1G, const float* __restrict__ LN1B,
    const float* __restrict__ LN2G, const float* __restrict__ LN2B,
    const float* __restrict__ HGW,  const float* __restrict__ HGB,
    const float* __restrict__ MLP1W, const float* __restrict__ MLP1B,
    const float* __restrict__ MLP2W, const float* __restrict__ MLP2B,
    const float* __restrict__ HMW,  const float* __restrict__ HMB,
    const float* __restrict__ G1W,  const float* __restrict__ G1B,
    const float* __restrict__ G2W,  const float* __restrict__ G2B,
    float* __restrict__ OUT)
{
    const int b = blockIdx.x;
    const int t = threadIdx.x;
    const int i  = t >> 1;
    const int o0 = (t & 1) * 32;

    __shared__ __align__(16) float sWh[128 * 68];   // 34816 B
    __shared__ __align__(16) float sH [128 * 68];   // 34816 B
    __shared__ __align__(16) u16   sW2[64 * 64];    //  8192 B (bf16)
    __shared__ __align__(16) float sEi[128];
    __shared__ __align__(16) float sEj[128];
    __shared__ __align__(16) float sScr[136];
    // total ~79.4 KB -> 2 blocks/CU

    // stage W2 -> LDS as bf16 (concurrent with P1). 4096 vals, 16 per thread.
    {
        const float4* src = (const float4*)(W2 + t * 16);
        u16 tmp[16];
        #pragma unroll
        for (int q = 0; q < 4; ++q) {
            float4 v = src[q];
            tmp[q * 4 + 0] = f2bf(v.x);
            tmp[q * 4 + 1] = f2bf(v.y);
            tmp[q * 4 + 2] = f2bf(v.z);
            tmp[q * 4 + 3] = f2bf(v.w);
        }
        uint4* dst = (uint4*)(sW2 + t * 16);
        dst[0] = ((const uint4*)tmp)[0];
        dst[1] = ((const uint4*)tmp)[1];
    }

    // P1: Wh1[i][o] = c[i]*W1[0][o] + sum_f emb[i][f]*W1[1+f][o]
    {
        float c = C[b * 128 + i];
        float4 e0 = *(const float4*)(EMB + i * 8);
        float4 e1 = *(const float4*)(EMB + i * 8 + 4);
        float emb[8] = { e0.x, e0.y, e0.z, e0.w, e1.x, e1.y, e1.z, e1.w };
        #pragma unroll
        for (int cc = 0; cc < 8; ++cc) {
            const int ob = o0 + cc * 4;
            float4 w0 = *(const float4*)(W1 + ob);
            float a0 = c * w0.x, a1 = c * w0.y, a2 = c * w0.z, a3 = c * w0.w;
            #pragma unroll
            for (int f = 0; f < 8; ++f) {
                float4 wf = *(const float4*)(W1 + (f + 1) * 64 + ob);
                a0 += emb[f] * wf.x; a1 += emb[f] * wf.y;
                a2 += emb[f] * wf.z; a3 += emb[f] * wf.w;
            }
            *(float4*)(sWh + i * 68 + ob) = make_float4(a0, a1, a2, a3);
        }
    }
    __syncthreads();

    // P2: e-vectors for layer 1
    if (t < 128) {
        float eiv = 0.f, ejv = 0.f;
        for (int o = 0; o < 64; o += 4) {
            float4 ai = *(const float4*)(A1 + o);
            float4 aj = *(const float4*)(A1 + 64 + o);
            const float* w = sWh + t * 68 + o;
            eiv += w[0] * ai.x + w[1] * ai.y + w[2] * ai.z + w[3] * ai.w;
            ejv += w[0] * aj.x + w[1] * aj.y + w[2] * aj.z + w[3] * aj.w;
        }
        sEi[t] = eiv; sEj[t] = ejv;
    }
    __syncthreads();

    // P3: GAT layer 1 (elu) + LN1 -> sH
    att_layer<true, false>(t, ADJ, sWh, sH, sEi, sEj, LN1G, LN1B);
    __syncthreads();

    // P4: Wh2 = sH @ W2 -> sWh
    {
        float acc[32];
        #pragma unroll
        for (int q = 0; q < 32; ++q) acc[q] = 0.f;
        for (int k2 = 0; k2 < 64; ++k2) {
            float h = sH[i * 68 + k2];
            const uint4* wp = (const uint4*)(sW2 + k2 * 64 + o0);
            #pragma unroll
            for (int q = 0; q < 4; ++q) {
                float w8[8]; unpack8(wp[q], w8);
                #pragma unroll
                for (int k = 0; k < 8; ++k) acc[q * 8 + k] += h * w8[k];
            }
        }
        float4* dst = (float4*)(sWh + i * 68 + o0);
        #pragma unroll
        for (int q = 0; q < 8; ++q)
            dst[q] = make_float4(acc[q * 4], acc[q * 4 + 1], acc[q * 4 + 2], acc[q * 4 + 3]);
    }
    __syncthreads();

    // P2': e-vectors for layer 2
    if (t < 128) {
        float eiv = 0.f, ejv = 0.f;
        for (int o = 0; o < 64; o += 4) {
            float4 ai = *(const float4*)(A2 + o);
            float4 aj = *(const float4*)(A2 + 64 + o);
            const float* w = sWh + t * 68 + o;
            eiv += w[0] * ai.x + w[1] * ai.y + w[2] * ai.z + w[3] * ai.w;
            ejv += w[0] * aj.x + w[1] * aj.y + w[2] * aj.z + w[3] * aj.w;
        }
        sEi[t] = eiv; sEj[t] = ejv;
    }
    __syncthreads();

    // P5: GAT layer 2 (no elu) + residual relu + LN2 -> sH
    att_layer<false, true>(t, ADJ, sWh, sH, sEi, sEj, LN2G, LN2B);
    __syncthreads();

    // P6: heads
    const int wvid = t >> 6;
    const int lane = t & 63;
    if (wvid == 0) {
        // q_gat = mean over rows of sH, dot head_gat_w
        float s = 0.f;
        for (int r2 = 0; r2 < 128; ++r2) s += sH[r2 * 68 + lane];
        float p = (s * (1.f / 128.f)) * HGW[lane];
        #pragma unroll
        for (int off = 32; off >= 1; off >>= 1) p += __shfl_down(p, off);
        if (lane == 0) sScr[128] = p + HGB[0];
    } else if (wvid == 1) {
        // x1 = relu(c @ mlp1_w + b)
        float a = 0.f;
        for (int k = 0; k < 128; ++k) a += C[b * 128 + k] * MLP1W[k * 64 + lane];
        sScr[lane] = fmaxf(a + MLP1B[lane], 0.f);
    } else if (wvid == 2) {
        // g1 = relu(c @ gate1_w + b)
        float a = 0.f;
        for (int k = 0; k < 128; ++k) a += C[b * 128 + k] * G1W[k * 64 + lane];
        sScr[64 + lane] = fmaxf(a + G1B[lane], 0.f);
    }
    __syncthreads();
    if (wvid == 0) {
        float a = 0.f;
        for (int k = 0; k < 64; ++k) a += sScr[k] * MLP2W[k * 64 + lane];
        float x2 = fmaxf(a + MLP2B[lane], 0.f);
        float p1 = x2 * HMW[lane];
        float p2 = sScr[64 + lane] * G2W[lane];
        #pragma unroll
        for (int off = 32; off >= 1; off >>= 1) {
            p1 += __shfl_down(p1, off);
            p2 += __shfl_down(p2, off);
        }
        if (lane == 0) {
            float q_mlp = p1 + HMB[0];
            float gpre  = p2 + G2B[0];
            float gate  = 1.f / (1.f + __expf(-gpre));
            OUT[b] = q_mlp + gate * sScr[128];
        }
    }
}

extern "C" void kernel_launch(void* const* d_in, const int* in_sizes, int n_in,
                              void* d_out, int out_size, void* d_ws, size_t ws_size,
                              hipStream_t stream) {
    (void)n_in; (void)out_size; (void)d_ws; (void)ws_size;
    const float* C     = (const float*)d_in[0];
    const float* ADJ   = (const float*)d_in[1];
    const float* EMB   = (const float*)d_in[2];
    const float* W1    = (const float*)d_in[3];
    const float* A1    = (const float*)d_in[4];
    const float* W2    = (const float*)d_in[5];
    const float* A2    = (const float*)d_in[6];
    const float* LN1G  = (const float*)d_in[7];
    const float* LN1B  = (const float*)d_in[8];
    const float* LN2G  = (const float*)d_in[9];
    const float* LN2B  = (const float*)d_in[10];
    const float* HGW   = (const float*)d_in[11];
    const float* HGB   = (const float*)d_in[12];
    const float* MLP1W = (const float*)d_in[13];
    const float* MLP1B = (const float*)d_in[14];
    const float* MLP2W = (const float*)d_in[15];
    const float* MLP2B = (const float*)d_in[16];
    const float* HMW   = (const float*)d_in[17];
    const float* HMB   = (const float*)d_in[18];
    const float* G1W   = (const float*)d_in[19];
    const float* G1B   = (const float*)d_in[20];
    const float* G2W   = (const float*)d_in[21];
    const float* G2B   = (const float*)d_in[22];

    const int B = in_sizes[0] / 128;  // 1024

    graphmixer_kernel<<<dim3(B), dim3(256), 0, stream>>>(
        C, ADJ, EMB, W1, A1, W2, A2, LN1G, LN1B, LN2G, LN2B,
        HGW, HGB, MLP1W, MLP1B, MLP2W, MLP2B, HMW, HMB,
        G1W, G1B, G2W, G2B, (float*)d_out);
}

// Round 3
// 149.373 us; speedup vs baseline: 1.8781x; 1.8781x over previous
//
#include <hip/hip_runtime.h>

typedef unsigned short u16;
typedef unsigned int u32;
typedef short v8s __attribute__((ext_vector_type(8)));
typedef float v4f __attribute__((ext_vector_type(4)));

__device__ __forceinline__ float bflo(u32 d){union{u32 i;float f;}u;u.i=d<<16;return u.f;}
__device__ __forceinline__ float bfhi(u32 d){union{u32 i;float f;}u;u.i=d&0xffff0000u;return u.f;}
__device__ __forceinline__ u16 f2bfr(float f){union{float f;u32 i;}u;u.f=f;return (u16)((u.i+0x8000u)>>16);}
__device__ __forceinline__ u32 pk2bf(float a,float b){
    union{float f;u32 i;}ua,ub; ua.f=a; ub.f=b;
    return ((ua.i+0x8000u)>>16)|((ub.i+0x8000u)&0xffff0000u);
}

// S[i][j] = adj>0 ? exp(lrelu(ei+ej))*adj : 0  (bf16, unnormalized); sRD[i] = 1/rowsum.
__device__ __forceinline__ void s_phase(int t, const float* __restrict__ ADJ,
                                        const float* __restrict__ sEi, const float* __restrict__ sEj,
                                        u16* __restrict__ sS, float* __restrict__ sRD)
{
    const int si = t >> 1, jh = (t & 1) * 64;
    const float ei = sEi[si];
    const float4* arow = (const float4*)(ADJ + si * 128 + jh);
    u16* srow = sS + si * 136 + jh;
    float D = 0.f;
    for (int q = 0; q < 8; ++q) {
        float4 a0 = arow[q*2+0];
        float4 a1 = arow[q*2+1];
        const float4* ejp = (const float4*)(sEj + jh + q*8);
        float4 e0 = ejp[0], e1 = ejp[1];
        float av[8] = {a0.x,a0.y,a0.z,a0.w,a1.x,a1.y,a1.z,a1.w};
        float ev[8] = {e0.x,e0.y,e0.z,e0.w,e1.x,e1.y,e1.z,e1.w};
        float w[8];
        #pragma unroll
        for (int k = 0; k < 8; ++k) {
            float e = ei + ev[k];
            e = (e >= 0.f) ? e : 0.2f * e;
            float ww = __expf(e) * av[k];
            ww = (av[k] > 0.f) ? ww : 0.f;
            w[k] = ww;
            D += ww;
        }
        uint4 pk;
        pk.x = pk2bf(w[0], w[1]); pk.y = pk2bf(w[2], w[3]);
        pk.z = pk2bf(w[4], w[5]); pk.w = pk2bf(w[6], w[7]);
        *(uint4*)(srow + q*8) = pk;
    }
    D += __shfl_xor(D, 1);
    if ((t & 1) == 0) sRD[si] = 1.f / D;
}

// acc[strip][ct] over 2 strips (wv, wv+4), 4 col tiles, K = nK*32.
__device__ __forceinline__ void pv_mfma(const u16* __restrict__ sA, int strA,
                                        const u16* __restrict__ sB, int strB,
                                        int nK, int wv, int l15, int q4, v4f acc[2][4])
{
    #pragma unroll
    for (int ks = 0; ks < 4; ++ks) {
        if (ks >= nK) break;
        const int ko = ks*32 + q4*8;
        v8s A0 = *(const v8s*)(sA + (16*wv     + l15)*strA + ko);
        v8s A1 = *(const v8s*)(sA + (16*(wv+4) + l15)*strA + ko);
        #pragma unroll
        for (int ct = 0; ct < 4; ++ct) {
            v8s B = *(const v8s*)(sB + (16*ct + l15)*strB + ko);
            acc[0][ct] = __builtin_amdgcn_mfma_f32_16x16x32_bf16(A0, B, acc[0][ct], 0,0,0);
            acc[1][ct] = __builtin_amdgcn_mfma_f32_16x16x32_bf16(A1, B, acc[1][ct], 0,0,0);
        }
    }
}

__global__ __launch_bounds__(256, 2) void graphmixer_kernel(
    const float* __restrict__ C,     // (1024,128)
    const float* __restrict__ ADJ,   // (128,128)
    const float* __restrict__ EMB,   // (128,8)
    const float* __restrict__ W1,    // (9,64)
    const float* __restrict__ A1,    // (128)
    const float* __restrict__ W2,    // (64,64)
    const float* __restrict__ A2,    // (128)
    const float* __restrict__ LN1G, const float* __restrict__ LN1B,
    const float* __restrict__ LN2G, const float* __restrict__ LN2B,
    const float* __restrict__ HGW,  const float* __restrict__ HGB,
    const float* __restrict__ MLP1W, const float* __restrict__ MLP1B,
    const float* __restrict__ MLP2W, const float* __restrict__ MLP2B,
    const float* __restrict__ HMW,  const float* __restrict__ HMB,
    const float* __restrict__ G1W,  const float* __restrict__ G1B,
    const float* __restrict__ G2W,  const float* __restrict__ G2B,
    float* __restrict__ OUT)
{
    const int b = blockIdx.x, t = threadIdx.x;
    const int lane = t & 63, wv = t >> 6;
    const int l15 = lane & 15, q4 = lane >> 4;

    __shared__ __align__(16) unsigned char smem[74400];
    u16*   sS   = (u16*)(smem);            // [128][136] bf16  (34816 B)
    u16*   sWhT = (u16*)(smem + 34816);    // [64][136]  bf16  WhT[o][i] (17408 B)
    u16*   sH1  = (u16*)(smem + 52224);    // [128][72]  bf16  (18432 B)
    float* sEi  = (float*)(smem + 70656);
    float* sEj  = (float*)(smem + 71168);
    float* sRD  = (float*)(smem + 71680);
    float* v2i  = (float*)(smem + 72192);  // 64
    float* v2j  = (float*)(smem + 72448);  // 64
    float* v1i  = (float*)(smem + 72704);  // 9
    float* v1j  = (float*)(smem + 72768);  // 9
    float* colp = (float*)(smem + 72832);  // 4*64
    float* sScr = (float*)(smem + 73856);  // 136
    // aliases inside the sS region (dead at those times):
    float* sEmb = (float*)(smem);          // 1024 f32, live P0..P1
    float* sC   = (float*)(smem + 4096);   // 128 f32,  live P0..P1
    u16*   sW2T = (u16*)(smem);            // [64][72] bf16, live P5c..P6

    // ---------- P0: stage c/emb, fold a-vectors ----------
    ((float4*)sEmb)[t] = ((const float4*)EMB)[t];          // 1024 floats
    if (t < 32) ((float4*)sC)[t] = ((const float4*)(C + b*128))[t];
    if (t >= 128 && t < 192) {           // v2i[k] = W2[k][:] . a2_i
        int k = t - 128; float a = 0.f;
        for (int q = 0; q < 16; ++q) {
            float4 w = *(const float4*)(W2 + k*64 + q*4);
            float4 x = *(const float4*)(A2 + q*4);
            a += w.x*x.x + w.y*x.y + w.z*x.z + w.w*x.w;
        }
        v2i[k] = a;
    } else if (t >= 192) {               // v2j[k] = W2[k][:] . a2_j
        int k = t - 192; float a = 0.f;
        for (int q = 0; q < 16; ++q) {
            float4 w = *(const float4*)(W2 + k*64 + q*4);
            float4 x = *(const float4*)(A2 + 64 + q*4);
            a += w.x*x.x + w.y*x.y + w.z*x.z + w.w*x.w;
        }
        v2j[k] = a;
    }
    if (t < 9) {                          // v1i[f] = W1[f][:] . a1_i
        float a = 0.f;
        for (int q = 0; q < 16; ++q) {
            float4 w = *(const float4*)(W1 + t*64 + q*4);
            float4 x = *(const float4*)(A1 + q*4);
            a += w.x*x.x + w.y*x.y + w.z*x.z + w.w*x.w;
        }
        v1i[t] = a;
    } else if (t >= 16 && t < 25) {       // v1j
        int f = t - 16; float a = 0.f;
        for (int q = 0; q < 16; ++q) {
            float4 w = *(const float4*)(W1 + f*64 + q*4);
            float4 x = *(const float4*)(A1 + 64 + q*4);
            a += w.x*x.x + w.y*x.y + w.z*x.z + w.w*x.w;
        }
        v1j[f] = a;
    }
    __syncthreads();   // b1

    // ---------- P1: Wh1T[o][i] (bf16) + e-vectors layer 1 ----------
    {
        const int o = lane, cc = wv;          // col o, rows cc*32..cc*32+31
        float w1f[9];
        #pragma unroll
        for (int f = 0; f < 9; ++f) w1f[f] = W1[f*64 + o];
        float whv[32];
        for (int i = 0; i < 32; ++i) {
            const int ig = cc*32 + i;
            float a = sC[ig] * w1f[0];
            const float4* ep = (const float4*)(sEmb + ig*8);
            float4 e0 = ep[0], e1 = ep[1];
            a += e0.x*w1f[1] + e0.y*w1f[2] + e0.z*w1f[3] + e0.w*w1f[4];
            a += e1.x*w1f[5] + e1.y*w1f[6] + e1.z*w1f[7] + e1.w*w1f[8];
            whv[i] = a;
        }
        u32 p[16];
        #pragma unroll
        for (int q = 0; q < 16; ++q) p[q] = pk2bf(whv[2*q], whv[2*q+1]);
        uint4* dst = (uint4*)(sWhT + o*136 + cc*32);
        dst[0] = ((uint4*)p)[0]; dst[1] = ((uint4*)p)[1];
        dst[2] = ((uint4*)p)[2]; dst[3] = ((uint4*)p)[3];
    }
    if (t < 128) {    // ei1/ej1 from x_g . v1
        float c = sC[t];
        const float4* ep = (const float4*)(sEmb + t*8);
        float4 e0 = ep[0], e1 = ep[1];
        float ei = c*v1i[0] + e0.x*v1i[1]+e0.y*v1i[2]+e0.z*v1i[3]+e0.w*v1i[4]
                             + e1.x*v1i[5]+e1.y*v1i[6]+e1.z*v1i[7]+e1.w*v1i[8];
        float ej = c*v1j[0] + e0.x*v1j[1]+e0.y*v1j[2]+e0.z*v1j[3]+e0.w*v1j[4]
                             + e1.x*v1j[5]+e1.y*v1j[6]+e1.z*v1j[7]+e1.w*v1j[8];
        sEi[t] = ei; sEj[t] = ej;
    }
    __syncthreads();   // b2

    // ---------- P3: S1 ----------
    s_phase(t, ADJ, sEi, sEj, sS, sRD);
    __syncthreads();   // b3

    // ---------- P4: h1' = S1 @ Wh1 ; P5: epilogue (1/D, ELU, LN1) -> sH1 ----------
    {
        v4f acc[2][4];
        #pragma unroll
        for (int s = 0; s < 2; ++s)
            #pragma unroll
            for (int ct = 0; ct < 4; ++ct) acc[s][ct] = (v4f){0.f,0.f,0.f,0.f};
        pv_mfma(sS, 136, sWhT, 136, 4, wv, l15, q4, acc);

        float g4[4], b4[4];
        #pragma unroll
        for (int ct = 0; ct < 4; ++ct) { g4[ct] = LN1G[16*ct + l15]; b4[ct] = LN1B[16*ct + l15]; }
        #pragma unroll
        for (int s = 0; s < 2; ++s) {
            const int rbase = 16*(wv + 4*s) + 4*q4;
            #pragma unroll
            for (int reg = 0; reg < 4; ++reg) {
                const int row = rbase + reg;
                const float rd = sRD[row];
                float x[4], s1 = 0.f, s2 = 0.f;
                #pragma unroll
                for (int ct = 0; ct < 4; ++ct) {
                    float v = acc[s][ct][reg] * rd;
                    v = (v > 0.f) ? v : (__expf(v) - 1.f);      // ELU
                    x[ct] = v; s1 += v; s2 += v*v;
                }
                s1 += __shfl_xor(s1, 1); s2 += __shfl_xor(s2, 1);
                s1 += __shfl_xor(s1, 2); s2 += __shfl_xor(s2, 2);
                s1 += __shfl_xor(s1, 4); s2 += __shfl_xor(s2, 4);
                s1 += __shfl_xor(s1, 8); s2 += __shfl_xor(s2, 8);
                const float mean = s1 * (1.f/64.f);
                const float var  = s2 * (1.f/64.f) - mean*mean;
                const float rstd = rsqrtf(var + 1e-5f);
                #pragma unroll
                for (int ct = 0; ct < 4; ++ct) {
                    float h = (x[ct] - mean) * rstd * g4[ct] + b4[ct];
                    sH1[row*72 + 16*ct + l15] = f2bfr(h);
                }
            }
        }
    }
    __syncthreads();   // b4

    // ---------- P5b: e-vectors layer 2 (h1 . v2)  |  P5c: stage W2T ----------
    if (t < 128) {
        float ei = 0.f, ej = 0.f;
        const u16* hrow = sH1 + t*72;
        for (int q = 0; q < 16; ++q) {
            uint2 d = *(const uint2*)(hrow + q*4);
            float h0 = bflo(d.x), h1v = bfhi(d.x), h2 = bflo(d.y), h3 = bfhi(d.y);
            ei += h0*v2i[q*4+0] + h1v*v2i[q*4+1] + h2*v2i[q*4+2] + h3*v2i[q*4+3];
            ej += h0*v2j[q*4+0] + h1v*v2j[q*4+1] + h2*v2j[q*4+2] + h3*v2j[q*4+3];
        }
        sEi[t] = ei; sEj[t] = ej;
    }
    {   // W2T[n][k] = W2[k][n], bf16 (coalesced read, scattered LDS write)
        #pragma unroll
        for (int q = 0; q < 4; ++q) {
            float4 v = ((const float4*)W2)[t*4 + q];
            int e = t*16 + q*4;
            int k = e >> 6, n = e & 63;
            sW2T[(n+0)*72 + k] = f2bfr(v.x);
            sW2T[(n+1)*72 + k] = f2bfr(v.y);
            sW2T[(n+2)*72 + k] = f2bfr(v.z);
            sW2T[(n+3)*72 + k] = f2bfr(v.w);
        }
    }
    __syncthreads();   // b5

    // ---------- P6: Wh2 = h1 @ W2 -> sWhT (transposed) ----------
    {
        v4f acc2[2][4];
        #pragma unroll
        for (int s = 0; s < 2; ++s)
            #pragma unroll
            for (int ct = 0; ct < 4; ++ct) acc2[s][ct] = (v4f){0.f,0.f,0.f,0.f};
        pv_mfma(sH1, 72, sW2T, 72, 2, wv, l15, q4, acc2);
        #pragma unroll
        for (int s = 0; s < 2; ++s) {
            const int rb = 16*(wv + 4*s) + 4*q4;
            #pragma unroll
            for (int ct = 0; ct < 4; ++ct) {
                const int col = 16*ct + l15;
                uint2 p;
                p.x = pk2bf(acc2[s][ct][0], acc2[s][ct][1]);
                p.y = pk2bf(acc2[s][ct][2], acc2[s][ct][3]);
                *(uint2*)(sWhT + col*136 + rb) = p;
            }
        }
    }
    __syncthreads();   // b6

    // ---------- P7: S2 ----------
    s_phase(t, ADJ, sEi, sEj, sS, sRD);
    __syncthreads();   // b7

    // ---------- P8: h2' = S2 @ Wh2 ; P9: epilogue (1/D, +h1 relu, LN2, colsum) ----------
    {
        v4f acc[2][4];
        #pragma unroll
        for (int s = 0; s < 2; ++s)
            #pragma unroll
            for (int ct = 0; ct < 4; ++ct) acc[s][ct] = (v4f){0.f,0.f,0.f,0.f};
        pv_mfma(sS, 136, sWhT, 136, 4, wv, l15, q4, acc);

        float g4[4], b4[4], colsum[4];
        #pragma unroll
        for (int ct = 0; ct < 4; ++ct) {
            g4[ct] = LN2G[16*ct + l15]; b4[ct] = LN2B[16*ct + l15]; colsum[ct] = 0.f;
        }
        #pragma unroll
        for (int s = 0; s < 2; ++s) {
            const int rbase = 16*(wv + 4*s) + 4*q4;
            #pragma unroll
            for (int reg = 0; reg < 4; ++reg) {
                const int row = rbase + reg;
                const float rd = sRD[row];
                float x[4], s1 = 0.f, s2 = 0.f;
                #pragma unroll
                for (int ct = 0; ct < 4; ++ct) {
                    float h1v = bflo((u32)sH1[row*72 + 16*ct + l15]);
                    float v = fmaxf(acc[s][ct][reg] * rd + h1v, 0.f);
                    x[ct] = v; s1 += v; s2 += v*v;
                }
                s1 += __shfl_xor(s1, 1); s2 += __shfl_xor(s2, 1);
                s1 += __shfl_xor(s1, 2); s2 += __shfl_xor(s2, 2);
                s1 += __shfl_xor(s1, 4); s2 += __shfl_xor(s2, 4);
                s1 += __shfl_xor(s1, 8); s2 += __shfl_xor(s2, 8);
                const float mean = s1 * (1.f/64.f);
                const float var  = s2 * (1.f/64.f) - mean*mean;
                const float rstd = rsqrtf(var + 1e-5f);
                #pragma unroll
                for (int ct = 0; ct < 4; ++ct) {
                    float h = (x[ct] - mean) * rstd * g4[ct] + b4[ct];
                    colsum[ct] += h;
                }
            }
        }
        #pragma unroll
        for (int ct = 0; ct < 4; ++ct) {
            colsum[ct] += __shfl_xor(colsum[ct], 16);
            colsum[ct] += __shfl_xor(colsum[ct], 32);
        }
        if (lane < 16) {
            #pragma unroll
            for (int ct = 0; ct < 4; ++ct) colp[wv*64 + ct*16 + lane] = colsum[ct];
        }
    }
    __syncthreads();   // b8

    // ---------- P10a: heads ----------
    const float* Cb = C + b*128;
    if (wv == 0) {
        float s = colp[lane] + colp[64 + lane] + colp[128 + lane] + colp[192 + lane];
        float p = s * (1.f/128.f) * HGW[lane];
        #pragma unroll
        for (int off = 32; off >= 1; off >>= 1) p += __shfl_down(p, off);
        if (lane == 0) sScr[128] = p + HGB[0];
    } else if (wv == 1) {
        float a = 0.f;
        for (int k = 0; k < 128; k += 4) {
            float4 c4 = *(const float4*)(Cb + k);
            a += c4.x*MLP1W[k*64+lane] + c4.y*MLP1W[(k+1)*64+lane]
               + c4.z*MLP1W[(k+2)*64+lane] + c4.w*MLP1W[(k+3)*64+lane];
        }
        sScr[lane] = fmaxf(a + MLP1B[lane], 0.f);
    } else if (wv == 2) {
        float a = 0.f;
        for (int k = 0; k < 128; k += 4) {
            float4 c4 = *(const float4*)(Cb + k);
            a += c4.x*G1W[k*64+lane] + c4.y*G1W[(k+1)*64+lane]
               + c4.z*G1W[(k+2)*64+lane] + c4.w*G1W[(k+3)*64+lane];
        }
        sScr[64 + lane] = fmaxf(a + G1B[lane], 0.f);
    }
    __syncthreads();   // b9

    // ---------- P10b: final combine ----------
    if (wv == 0) {
        float a = 0.f;
        for (int k = 0; k < 64; ++k) a += sScr[k] * MLP2W[k*64 + lane];
        float x2 = fmaxf(a + MLP2B[lane], 0.f);
        float p1 = x2 * HMW[lane];
        float p2 = sScr[64 + lane] * G2W[lane];
        #pragma unroll
        for (int off = 32; off >= 1; off >>= 1) {
            p1 += __shfl_down(p1, off);
            p2 += __shfl_down(p2, off);
        }
        if (lane == 0) {
            float q_mlp = p1 + HMB[0];
            float gpre  = p2 + G2B[0];
            float gate  = 1.f / (1.f + __expf(-gpre));
            OUT[b] = q_mlp + gate * sScr[128];
        }
    }
}

extern "C" void kernel_launch(void* const* d_in, const int* in_sizes, int n_in,
                              void* d_out, int out_size, void* d_ws, size_t ws_size,
                              hipStream_t stream) {
    (void)n_in; (void)out_size; (void)d_ws; (void)ws_size;
    const float* C     = (const float*)d_in[0];
    const float* ADJ   = (const float*)d_in[1];
    const float* EMB   = (const float*)d_in[2];
    const float* W1    = (const float*)d_in[3];
    const float* A1    = (const float*)d_in[4];
    const float* W2    = (const float*)d_in[5];
    const float* A2    = (const float*)d_in[6];
    const float* LN1G  = (const float*)d_in[7];
    const float* LN1B  = (const float*)d_in[8];
    const float* LN2G  = (const float*)d_in[9];
    const float* LN2B  = (const float*)d_in[10];
    const float* HGW   = (const float*)d_in[11];
    const float* HGB   = (const float*)d_in[12];
    const float* MLP1W = (const float*)d_in[13];
    const float* MLP1B = (const float*)d_in[14];
    const float* MLP2W = (const float*)d_in[15];
    const float* MLP2B = (const float*)d_in[16];
    const float* HMW   = (const float*)d_in[17];
    const float* HMB   = (const float*)d_in[18];
    const float* G1W   = (const float*)d_in[19];
    const float* G1B   = (const float*)d_in[20];
    const float* G2W   = (const float*)d_in[21];
    const float* G2B   = (const float*)d_in[22];

    const int B = in_sizes[0] / 128;  // 1024

    graphmixer_kernel<<<dim3(B), dim3(256), 0, stream>>>(
        C, ADJ, EMB, W1, A1, W2, A2, LN1G, LN1B, LN2G, LN2B,
        HGW, HGB, MLP1W, MLP1B, MLP2W, MLP2B, HMW, HMB,
        G1W, G1B, G2W, G2B, (float*)d_out);
}

// Round 4
// 129.593 us; speedup vs baseline: 2.1648x; 1.1526x over previous
//
#include <hip/hip_runtime.h>

typedef unsigned short u16;
typedef unsigned int u32;
typedef short v8s __attribute__((ext_vector_type(8)));
typedef float v4f __attribute__((ext_vector_type(4)));

__device__ __forceinline__ float bflo(u32 d){union{u32 i;float f;}u;u.i=d<<16;return u.f;}
__device__ __forceinline__ float bfhi(u32 d){union{u32 i;float f;}u;u.i=d&0xffff0000u;return u.f;}
__device__ __forceinline__ u16 f2bfr(float f){union{float f;u32 i;}u;u.f=f;return (u16)((u.i+0x8000u)>>16);}
__device__ __forceinline__ u32 pk2bf(float a,float b){
    union{float f;u32 i;}ua,ub; ua.f=a; ub.f=b;
    return ((ua.i+0x8000u)>>16)|((ub.i+0x8000u)&0xffff0000u);
}
__device__ __forceinline__ v8s pack8(const float* w){
    union { uint4 u; v8s v; } c;
    c.u.x = pk2bf(w[0],w[1]); c.u.y = pk2bf(w[2],w[3]);
    c.u.z = pk2bf(w[4],w[5]); c.u.w = pk2bf(w[6],w[7]);
    return c.v;
}

// Flash S@Wh: A-fragment (unnormalized softmax weights) generated in registers,
// MFMA'd against B = sWhT[o][i] (stride 136). Returns acc[strip][ct] and invD[strip].
__device__ __forceinline__ void flash_att(
    int wv, int l15, int q4,
    const float* __restrict__ ADJ,
    const float* __restrict__ sEi, const float* __restrict__ sEj,
    const u16* __restrict__ sWhT,
    v4f acc[2][4], float invD[2])
{
    const int r0 = 16*wv + l15, r1 = r0 + 64;
    const float ei0 = sEi[r0], ei1 = sEi[r1];
    float D0 = 0.f, D1 = 0.f;
    #pragma unroll
    for (int s = 0; s < 2; ++s)
        #pragma unroll
        for (int ct = 0; ct < 4; ++ct) acc[s][ct] = (v4f){0.f,0.f,0.f,0.f};

    for (int ks = 0; ks < 4; ++ks) {
        const int ko = ks*32 + q4*8;
        float ej[8];
        *(float4*)(ej)     = *(const float4*)(sEj + ko);
        *(float4*)(ej + 4) = *(const float4*)(sEj + ko + 4);
        float4 a00 = *(const float4*)(ADJ + r0*128 + ko);
        float4 a01 = *(const float4*)(ADJ + r0*128 + ko + 4);
        float4 a10 = *(const float4*)(ADJ + r1*128 + ko);
        float4 a11 = *(const float4*)(ADJ + r1*128 + ko + 4);
        float av0[8] = {a00.x,a00.y,a00.z,a00.w,a01.x,a01.y,a01.z,a01.w};
        float av1[8] = {a10.x,a10.y,a10.z,a10.w,a11.x,a11.y,a11.z,a11.w};
        float w0[8], w1[8];
        #pragma unroll
        for (int k = 0; k < 8; ++k) {
            float e0 = ei0 + ej[k]; e0 = fmaxf(e0, 0.2f*e0);     // leaky-relu
            float e1 = ei1 + ej[k]; e1 = fmaxf(e1, 0.2f*e1);
            float x0 = __expf(e0) * av0[k];                      // adj>=0: adj==0 -> w==0
            float x1 = __expf(e1) * av1[k];
            w0[k] = x0; w1[k] = x1; D0 += x0; D1 += x1;
        }
        v8s A0 = pack8(w0), A1 = pack8(w1);
        #pragma unroll
        for (int ct = 0; ct < 4; ++ct) {
            v8s B = *(const v8s*)(sWhT + (16*ct + l15)*136 + ko);
            acc[0][ct] = __builtin_amdgcn_mfma_f32_16x16x32_bf16(A0, B, acc[0][ct], 0,0,0);
            acc[1][ct] = __builtin_amdgcn_mfma_f32_16x16x32_bf16(A1, B, acc[1][ct], 0,0,0);
        }
    }
    D0 += __shfl_xor(D0, 16); D0 += __shfl_xor(D0, 32);
    D1 += __shfl_xor(D1, 16); D1 += __shfl_xor(D1, 32);
    invD[0] = 1.f / D0; invD[1] = 1.f / D1;
}

__global__ __launch_bounds__(256, 4) void graphmixer_kernel(
    const float* __restrict__ C,     // (1024,128)
    const float* __restrict__ ADJ,   // (128,128)
    const float* __restrict__ EMB,   // (128,8)
    const float* __restrict__ W1,    // (9,64)
    const float* __restrict__ A1,    // (128)
    const float* __restrict__ W2,    // (64,64)
    const float* __restrict__ A2,    // (128)
    const float* __restrict__ LN1G, const float* __restrict__ LN1B,
    const float* __restrict__ LN2G, const float* __restrict__ LN2B,
    const float* __restrict__ HGW,  const float* __restrict__ HGB,
    const float* __restrict__ MLP1W, const float* __restrict__ MLP1B,
    const float* __restrict__ MLP2W, const float* __restrict__ MLP2B,
    const float* __restrict__ HMW,  const float* __restrict__ HMB,
    const float* __restrict__ G1W,  const float* __restrict__ G1B,
    const float* __restrict__ G2W,  const float* __restrict__ G2B,
    float* __restrict__ OUT)
{
    const int b = blockIdx.x, t = threadIdx.x;
    const int lane = t & 63, wv = t >> 6;
    const int l15 = lane & 15, q4 = lane >> 4;

    __shared__ __align__(16) unsigned char smem[39072];
    u16*   sWhT = (u16*)(smem);            // [64][136] bf16 : Wh1T then Wh2T  (17408)
    u16*   sH1  = (u16*)(smem + 17408);    // [128][72] bf16                    (18432)
    float* sEi  = (float*)(smem + 35840);  // 128
    float* sEj  = (float*)(smem + 36352);  // 128
    float* colp = (float*)(smem + 36864);  // 256
    float* sScr = (float*)(smem + 37888);  // 136
    float* v2i  = (float*)(smem + 38432);  // 64
    float* v2j  = (float*)(smem + 38688);  // 64
    float* v1i  = (float*)(smem + 38944);  // 9 (pad 16)
    float* v1j  = (float*)(smem + 39008);  // 9 (pad 16)
    // aliases in the sH1 region (dead until P4 epilogue):
    float* sEmb = (float*)(smem + 17408);  // 1024 f32
    float* sC   = (float*)(smem + 21504);  // 128 f32

    const float* Cb = C + b*128;

    // ================= P0 =================
    if (wv == 0) {
        #pragma unroll
        for (int q = 0; q < 4; ++q)
            ((float4*)sEmb)[lane + 64*q] = ((const float4*)EMB)[lane + 64*q];
        if (lane < 32) ((float4*)sC)[lane] = ((const float4*)Cb)[lane];
        if (lane >= 32 && lane < 41) {            // v1i[f] = W1[f][:] . a1_i
            int f = lane - 32; float a = 0.f;
            for (int q = 0; q < 16; ++q) {
                float4 w = *(const float4*)(W1 + f*64 + q*4);
                float4 x = *(const float4*)(A1 + q*4);
                a += w.x*x.x + w.y*x.y + w.z*x.z + w.w*x.w;
            }
            v1i[f] = a;
        } else if (lane >= 48 && lane < 57) {     // v1j
            int f = lane - 48; float a = 0.f;
            for (int q = 0; q < 16; ++q) {
                float4 w = *(const float4*)(W1 + f*64 + q*4);
                float4 x = *(const float4*)(A1 + 64 + q*4);
                a += w.x*x.x + w.y*x.y + w.z*x.z + w.w*x.w;
            }
            v1j[f] = a;
        }
    } else if (wv == 3) {                         // v2i/v2j[k] = W2[k][:] . a2_{i,j}
        float ai = 0.f, aj = 0.f;
        for (int q = 0; q < 16; ++q) {
            float4 w  = *(const float4*)(W2 + lane*64 + q*4);
            float4 xi = *(const float4*)(A2 + q*4);
            float4 xj = *(const float4*)(A2 + 64 + q*4);
            ai += w.x*xi.x + w.y*xi.y + w.z*xi.z + w.w*xi.w;
            aj += w.x*xj.x + w.y*xj.y + w.z*xj.z + w.w*xj.w;
        }
        v2i[lane] = ai; v2j[lane] = aj;
    } else if (wv == 1) {                         // q_mlp head (wave-private)
        float a = 0.f;
        for (int k = 0; k < 128; k += 4) {
            float4 c4 = *(const float4*)(Cb + k);
            a += c4.x*MLP1W[k*64+lane] + c4.y*MLP1W[(k+1)*64+lane]
               + c4.z*MLP1W[(k+2)*64+lane] + c4.w*MLP1W[(k+3)*64+lane];
        }
        sScr[lane] = fmaxf(a + MLP1B[lane], 0.f);
        float a2 = 0.f;
        for (int k = 0; k < 64; ++k) a2 += sScr[k] * MLP2W[k*64 + lane];
        float x2 = fmaxf(a2 + MLP2B[lane], 0.f);
        float p1 = x2 * HMW[lane];
        #pragma unroll
        for (int off = 32; off >= 1; off >>= 1) p1 += __shfl_down(p1, off);
        if (lane == 0) sScr[128] = p1 + HMB[0];
    } else {                                      // wv==2: gate head (wave-private)
        float a = 0.f;
        for (int k = 0; k < 128; k += 4) {
            float4 c4 = *(const float4*)(Cb + k);
            a += c4.x*G1W[k*64+lane] + c4.y*G1W[(k+1)*64+lane]
               + c4.z*G1W[(k+2)*64+lane] + c4.w*G1W[(k+3)*64+lane];
        }
        sScr[64 + lane] = fmaxf(a + G1B[lane], 0.f);
        float p2 = sScr[64 + lane] * G2W[lane];
        #pragma unroll
        for (int off = 32; off >= 1; off >>= 1) p2 += __shfl_down(p2, off);
        if (lane == 0) sScr[129] = 1.f / (1.f + __expf(-(p2 + G2B[0])));
    }
    __syncthreads();   // b1

    // ================= P1: Wh1T + e1-vectors =================
    {
        const int o = lane, cc = wv;
        float w1f[9];
        #pragma unroll
        for (int f = 0; f < 9; ++f) w1f[f] = W1[f*64 + o];
        float whv[32];
        for (int i = 0; i < 32; ++i) {
            const int ig = cc*32 + i;
            float a = sC[ig] * w1f[0];
            float4 e0 = *(const float4*)(sEmb + ig*8);
            float4 e1 = *(const float4*)(sEmb + ig*8 + 4);
            a += e0.x*w1f[1] + e0.y*w1f[2] + e0.z*w1f[3] + e0.w*w1f[4];
            a += e1.x*w1f[5] + e1.y*w1f[6] + e1.z*w1f[7] + e1.w*w1f[8];
            whv[i] = a;
        }
        u32 p[16];
        #pragma unroll
        for (int q = 0; q < 16; ++q) p[q] = pk2bf(whv[2*q], whv[2*q+1]);
        uint4* dst = (uint4*)(sWhT + o*136 + cc*32);
        dst[0] = ((uint4*)p)[0]; dst[1] = ((uint4*)p)[1];
        dst[2] = ((uint4*)p)[2]; dst[3] = ((uint4*)p)[3];
    }
    if (t < 128) {
        float c = sC[t];
        float4 e0 = *(const float4*)(sEmb + t*8);
        float4 e1 = *(const float4*)(sEmb + t*8 + 4);
        float ei = c*v1i[0] + e0.x*v1i[1]+e0.y*v1i[2]+e0.z*v1i[3]+e0.w*v1i[4]
                            + e1.x*v1i[5]+e1.y*v1i[6]+e1.z*v1i[7]+e1.w*v1i[8];
        float ej = c*v1j[0] + e0.x*v1j[1]+e0.y*v1j[2]+e0.z*v1j[3]+e0.w*v1j[4]
                            + e1.x*v1j[5]+e1.y*v1j[6]+e1.z*v1j[7]+e1.w*v1j[8];
        sEi[t] = ei; sEj[t] = ej;
    }
    __syncthreads();   // b2

    // ================= P4: flash S1@Wh1 + (1/D, ELU, LN1) -> sH1 =================
    {
        v4f acc[2][4]; float invD[2];
        flash_att(wv, l15, q4, ADJ, sEi, sEj, sWhT, acc, invD);

        float g4[4], b4[4];
        #pragma unroll
        for (int ct = 0; ct < 4; ++ct) { g4[ct] = LN1G[16*ct + l15]; b4[ct] = LN1B[16*ct + l15]; }
        #pragma unroll
        for (int s = 0; s < 2; ++s) {
            const int rbase = 16*(wv + 4*s) + 4*q4;
            #pragma unroll
            for (int reg = 0; reg < 4; ++reg) {
                const int row = rbase + reg;
                const float rd = __shfl(invD[s], 4*q4 + reg);
                float x[4], s1 = 0.f, s2 = 0.f;
                #pragma unroll
                for (int ct = 0; ct < 4; ++ct) {
                    float v = acc[s][ct][reg] * rd;
                    v = (v > 0.f) ? v : (__expf(v) - 1.f);      // ELU
                    x[ct] = v; s1 += v; s2 += v*v;
                }
                s1 += __shfl_xor(s1, 1); s2 += __shfl_xor(s2, 1);
                s1 += __shfl_xor(s1, 2); s2 += __shfl_xor(s2, 2);
                s1 += __shfl_xor(s1, 4); s2 += __shfl_xor(s2, 4);
                s1 += __shfl_xor(s1, 8); s2 += __shfl_xor(s2, 8);
                const float mean = s1 * (1.f/64.f);
                const float var  = s2 * (1.f/64.f) - mean*mean;
                const float rstd = rsqrtf(var + 1e-5f);
                #pragma unroll
                for (int ct = 0; ct < 4; ++ct) {
                    float h = (x[ct] - mean) * rstd * g4[ct] + b4[ct];
                    sH1[row*72 + 16*ct + l15] = f2bfr(h);
                }
            }
        }
    }
    __syncthreads();   // b4

    // ================= P5b: e2-vectors | P6: Wh2 = h1@W2 -> sWhT =================
    if (t < 128) {
        float ei = 0.f, ej = 0.f;
        const u16* hrow = sH1 + t*72;
        for (int q = 0; q < 16; ++q) {
            uint2 d = *(const uint2*)(hrow + q*4);
            float h0 = bflo(d.x), h1v = bfhi(d.x), h2 = bflo(d.y), h3 = bfhi(d.y);
            ei += h0*v2i[q*4+0] + h1v*v2i[q*4+1] + h2*v2i[q*4+2] + h3*v2i[q*4+3];
            ej += h0*v2j[q*4+0] + h1v*v2j[q*4+1] + h2*v2j[q*4+2] + h3*v2j[q*4+3];
        }
        sEi[t] = ei; sEj[t] = ej;
    }
    {
        v4f acc2[2][4];
        #pragma unroll
        for (int s = 0; s < 2; ++s)
            #pragma unroll
            for (int ct = 0; ct < 4; ++ct) acc2[s][ct] = (v4f){0.f,0.f,0.f,0.f};
        #pragma unroll
        for (int ks = 0; ks < 2; ++ks) {
            const int kb = ks*32 + q4*8;
            v8s Bf[4];
            #pragma unroll
            for (int ct = 0; ct < 4; ++ct) {
                const float* wp = W2 + kb*64 + 16*ct + l15;
                float w8[8];
                #pragma unroll
                for (int j = 0; j < 8; ++j) w8[j] = wp[j*64];
                Bf[ct] = pack8(w8);
            }
            #pragma unroll
            for (int s = 0; s < 2; ++s) {
                v8s A = *(const v8s*)(sH1 + (16*(wv+4*s) + l15)*72 + kb);
                #pragma unroll
                for (int ct = 0; ct < 4; ++ct)
                    acc2[s][ct] = __builtin_amdgcn_mfma_f32_16x16x32_bf16(A, Bf[ct], acc2[s][ct], 0,0,0);
            }
        }
        #pragma unroll
        for (int s = 0; s < 2; ++s) {
            const int rb = 16*(wv+4*s) + 4*q4;
            #pragma unroll
            for (int ct = 0; ct < 4; ++ct) {
                const int col = 16*ct + l15;
                uint2 p;
                p.x = pk2bf(acc2[s][ct][0], acc2[s][ct][1]);
                p.y = pk2bf(acc2[s][ct][2], acc2[s][ct][3]);
                *(uint2*)(sWhT + col*136 + rb) = p;
            }
        }
    }
    __syncthreads();   // b6

    // ================= P7: flash S2@Wh2 + (1/D, +h1 relu, LN2, colsum) =================
    {
        v4f acc[2][4]; float invD[2];
        flash_att(wv, l15, q4, ADJ, sEi, sEj, sWhT, acc, invD);

        float g4[4], b4[4], colsum[4];
        #pragma unroll
        for (int ct = 0; ct < 4; ++ct) {
            g4[ct] = LN2G[16*ct + l15]; b4[ct] = LN2B[16*ct + l15]; colsum[ct] = 0.f;
        }
        #pragma unroll
        for (int s = 0; s < 2; ++s) {
            const int rbase = 16*(wv + 4*s) + 4*q4;
            #pragma unroll
            for (int reg = 0; reg < 4; ++reg) {
                const int row = rbase + reg;
                const float rd = __shfl(invD[s], 4*q4 + reg);
                float x[4], s1 = 0.f, s2 = 0.f;
                #pragma unroll
                for (int ct = 0; ct < 4; ++ct) {
                    float h1v = bflo((u32)sH1[row*72 + 16*ct + l15]);
                    float v = fmaxf(acc[s][ct][reg] * rd + h1v, 0.f);
                    x[ct] = v; s1 += v; s2 += v*v;
                }
                s1 += __shfl_xor(s1, 1); s2 += __shfl_xor(s2, 1);
                s1 += __shfl_xor(s1, 2); s2 += __shfl_xor(s2, 2);
                s1 += __shfl_xor(s1, 4); s2 += __shfl_xor(s2, 4);
                s1 += __shfl_xor(s1, 8); s2 += __shfl_xor(s2, 8);
                const float mean = s1 * (1.f/64.f);
                const float var  = s2 * (1.f/64.f) - mean*mean;
                const float rstd = rsqrtf(var + 1e-5f);
                #pragma unroll
                for (int ct = 0; ct < 4; ++ct)
                    colsum[ct] += (x[ct] - mean) * rstd * g4[ct] + b4[ct];
            }
        }
        #pragma unroll
        for (int ct = 0; ct < 4; ++ct) {
            colsum[ct] += __shfl_xor(colsum[ct], 16);
            colsum[ct] += __shfl_xor(colsum[ct], 32);
        }
        if (lane < 16) {
            #pragma unroll
            for (int ct = 0; ct < 4; ++ct) colp[wv*64 + ct*16 + lane] = colsum[ct];
        }
    }
    __syncthreads();   // b8

    // ================= final combine (wave 0) =================
    if (wv == 0) {
        float s = colp[lane] + colp[64 + lane] + colp[128 + lane] + colp[192 + lane];
        float p = s * (1.f/128.f) * HGW[lane];
        #pragma unroll
        for (int off = 32; off >= 1; off >>= 1) p += __shfl_down(p, off);
        if (lane == 0) OUT[b] = sScr[128] + sScr[129] * (p + HGB[0]);
    }
}

extern "C" void kernel_launch(void* const* d_in, const int* in_sizes, int n_in,
                              void* d_out, int out_size, void* d_ws, size_t ws_size,
                              hipStream_t stream) {
    (void)n_in; (void)out_size; (void)d_ws; (void)ws_size;
    const float* C     = (const float*)d_in[0];
    const float* ADJ   = (const float*)d_in[1];
    const float* EMB   = (const float*)d_in[2];
    const float* W1    = (const float*)d_in[3];
    const float* A1    = (const float*)d_in[4];
    const float* W2    = (const float*)d_in[5];
    const float* A2    = (const float*)d_in[6];
    const float* LN1G  = (const float*)d_in[7];
    const float* LN1B  = (const float*)d_in[8];
    const float* LN2G  = (const float*)d_in[9];
    const float* LN2B  = (const float*)d_in[10];
    const float* HGW   = (const float*)d_in[11];
    const float* HGB   = (const float*)d_in[12];
    const float* MLP1W = (const float*)d_in[13];
    const float* MLP1B = (const float*)d_in[14];
    const float* MLP2W = (const float*)d_in[15];
    const float* MLP2B = (const float*)d_in[16];
    const float* HMW   = (const float*)d_in[17];
    const float* HMB   = (const float*)d_in[18];
    const float* G1W   = (const float*)d_in[19];
    const float* G1B   = (const float*)d_in[20];
    const float* G2W   = (const float*)d_in[21];
    const float* G2B   = (const float*)d_in[22];

    const int B = in_sizes[0] / 128;  // 1024

    graphmixer_kernel<<<dim3(B), dim3(256), 0, stream>>>(
        C, ADJ, EMB, W1, A1, W2, A2, LN1G, LN1B, LN2G, LN2B,
        HGW, HGB, MLP1W, MLP1B, MLP2W, MLP2B, HMW, HMB,
        G1W, G1B, G2W, G2B, (float*)d_out);
}